// Round 8
// baseline (182.031 us; speedup 1.0000x reference)
//
#include <hip/hip_runtime.h>
#include <stdint.h>

// ---------------------------------------------------------------------------
// MHA forward: fp32 in/out, internal bf16, fp32 accumulate.
//   B=4 S=2048 D=512 H=8 DH=64
//   pipeline: convert(fp32->bf16) -> merged QKV NT-GEMM (dbuf async staging,
//             LDS-coalesced bf16 epilogue) -> flash attention -> out-proj GEMM
// MFMA 16x16x32 bf16 layouts (HW-verified per guide):
//   A-frag: lane holds A[m=lane&15][k=(lane>>4)*8 + j], j=0..7 (contiguous)
//   B-frag: lane holds B[k=(lane>>4)*8 + j][n=lane&15]
//   C/D   : lane reg r holds D[row=(lane>>4)*4 + r][col=lane&15]
// Internal activation layout: flat [B*S, D] bf16 (row-major), head h = cols
// h*64..h*64+63. Same layout for qp/kp/vp/ao -> GEMM epilogues write plain
// row-major (coalescible) and attention indexes with row stride 512.
// ---------------------------------------------------------------------------

typedef __attribute__((ext_vector_type(8))) short short8;
typedef __attribute__((ext_vector_type(4))) short short4v;
typedef __attribute__((ext_vector_type(4))) float f32x4;
typedef __attribute__((ext_vector_type(4))) unsigned short u16x4;

#define MFMA16(a, b, c) __builtin_amdgcn_mfma_f32_16x16x32_bf16(a, b, c, 0, 0, 0)

#define SCALE_LOG2 0.18033688011112042f
#define FIXED_M    32.0f
#define MASKED_E2  -200.0f   // exp2(-200) == 0.0f exactly

__device__ __forceinline__ unsigned short f2bf(float f) {
    unsigned int x = __float_as_uint(f);
    unsigned int r = (x + 0x7fffu + ((x >> 16) & 1u)) >> 16;  // RNE
    return (unsigned short)r;
}
__device__ __forceinline__ short8 load8(const unsigned short* p) {
    return *reinterpret_cast<const short8*>(p);
}
// async 16B global -> LDS DMA (lane l lands at wave-uniform base + l*16)
__device__ __forceinline__ void gload_lds16(const unsigned short* g, unsigned short* l) {
    __builtin_amdgcn_global_load_lds(
        (const __attribute__((address_space(1))) unsigned int*)g,
        (__attribute__((address_space(3))) unsigned int*)l, 16, 0, 0);
}

// ---------------------------------------------------------------------------
// fp32 -> bf16 convert: Q,K,V (3 x 4.19M) + Wq,Wk,Wv,Wo (4 x 262144) into ws.
// ---------------------------------------------------------------------------
__global__ __launch_bounds__(256)
void convert_bf16(const float4* __restrict__ Q, const float4* __restrict__ K,
                  const float4* __restrict__ V, const float4* __restrict__ Wq,
                  const float4* __restrict__ Wk, const float4* __restrict__ Wv,
                  const float4* __restrict__ Wo, u16x4* __restrict__ dst)
{
    const int n = 3407872;
    for (int i = blockIdx.x * 256 + threadIdx.x; i < n; i += gridDim.x * 256) {
        const float4* src; int off;
        if      (i < 1048576) { src = Q;  off = i; }
        else if (i < 2097152) { src = K;  off = i - 1048576; }
        else if (i < 3145728) { src = V;  off = i - 2097152; }
        else if (i < 3211264) { src = Wq; off = i - 3145728; }
        else if (i < 3276800) { src = Wk; off = i - 3211264; }
        else if (i < 3342336) { src = Wv; off = i - 3276800; }
        else                  { src = Wo; off = i - 3342336; }
        const float4 v = src[off];
        u16x4 r;
        r[0] = f2bf(v.x); r[1] = f2bf(v.y); r[2] = f2bf(v.z); r[3] = f2bf(v.w);
        dst[i] = r;
    }
}

// ---------------------------------------------------------------------------
// NT GEMM, bf16 x bf16, 128x128 tile, BK=64, dbuf DMA staging, 4 waves.
// C[i][j] = sum_k A[i][k]*W[j][k] + bias[j];  A [8192,512], W [512,512].
// LDS (64 KB): buf b: A at SM+b*16384, B at SM+b*16384+8192 (u16 offsets).
// XOR chunk swizzle (c ^ (r&7)) -> conflict-free b128 frag reads, DMA-legal.
// K-loop: barrier -> issue DMA(it+1 -> other buf) -> compute(it). The
// compiler's vmcnt(0)-before-barrier then drains a DMA that had the whole
// compute phase to land -> staging latency hidden, 1 barrier/iter.
// Epilogue out_mode 0 (bf16): C tile through LDS -> 256 B-contiguous stores.
// out_mode 1 (fp32): direct stores (full 64 B sectors).
// ---------------------------------------------------------------------------
__global__ __launch_bounds__(256)
void gemm_bf(const unsigned short* __restrict__ Aall,
             const unsigned short* __restrict__ Wall,
             const float* __restrict__ b0, const float* __restrict__ b1,
             const float* __restrict__ b2,
             void* __restrict__ outall, int out_mode)
{
    __shared__ unsigned short SM[32768];   // 64 KB: 2 x (A 8192 + B 8192)

    const int z = blockIdx.y;
    const unsigned short* A = Aall + (long)z * 4194304;
    const unsigned short* W = Wall + z * 262144;
    const float* bias = (z == 0) ? b0 : (z == 1) ? b1 : b2;

    const int f    = blockIdx.x;       // 0..255, XCD swizzle
    const int xcd  = f & 7;
    const int slot = f >> 3;
    const int col0 = (slot & 3) * 128;
    const int row0 = ((slot >> 2) * 8 + xcd) * 128;

    const int tid  = threadIdx.x;
    const int lane = tid & 63;
    const int w    = tid >> 6;
    const int quad = lane >> 4;
    const int nlow = lane & 15;
    const int wm   = w >> 1, wn = w & 1;

    // staging descriptors: 4 DMA issues each for A and B per K-step
    const unsigned short* ag[4];
    const unsigned short* wg[4];
    int ldso[4];
#pragma unroll
    for (int i = 0; i < 4; i++) {
        const int s = i * 256 + tid;
        const int r = s >> 3, kcl = s & 7;
        const int kg = kcl ^ (r & 7);
        ag[i] = A + (long)(row0 + r) * 512 + kg * 8;
        wg[i] = W + (long)(col0 + r) * 512 + kg * 8;
        ldso[i] = i * 2048 + (w << 9);   // wave-uniform LDS base (u16)
    }

    f32x4 acc[4][4];
#pragma unroll
    for (int t = 0; t < 4; t++)
#pragma unroll
        for (int g = 0; g < 4; g++) acc[t][g] = (f32x4){0.f, 0.f, 0.f, 0.f};

    // prologue: tile 0 -> buf 0
#pragma unroll
    for (int i = 0; i < 4; i++) {
        gload_lds16(ag[i], SM + ldso[i]);
        gload_lds16(wg[i], SM + 8192 + ldso[i]);
    }

    for (int it = 0; it < 8; ++it) {
        __syncthreads();   // drains prev-iter prefetch (latency already hidden)
        if (it < 7) {
            const int nb = (it + 1) & 1;
            const int k0 = (it + 1) * 64;
#pragma unroll
            for (int i = 0; i < 4; i++) {
                gload_lds16(ag[i] + k0, SM + nb * 16384 + ldso[i]);
                gload_lds16(wg[i] + k0, SM + nb * 16384 + 8192 + ldso[i]);
            }
        }
        const unsigned short* A_ = SM + (it & 1) * 16384;
        const unsigned short* B_ = A_ + 8192;

        short8 af[4][2], bf[4][2];
#pragma unroll
        for (int t = 0; t < 4; t++) {
            const int rowa = wm * 64 + t * 16 + nlow;
            const int rowb = wn * 64 + t * 16 + nlow;
#pragma unroll
            for (int kc = 0; kc < 2; kc++) {
                const int c = (kc * 4 + quad) ^ (nlow & 7);
                af[t][kc] = load8(&A_[(rowa * 8 + c) * 8]);
                bf[t][kc] = load8(&B_[(rowb * 8 + c) * 8]);
            }
        }
#pragma unroll
        for (int kc = 0; kc < 2; kc++)
#pragma unroll
            for (int t = 0; t < 4; t++)
#pragma unroll
                for (int g = 0; g < 4; g++)
                    acc[t][g] = MFMA16(af[t][kc], bf[g][kc], acc[t][g]);
    }

    // bias (per g, col j known per lane)
    float bj[4];
#pragma unroll
    for (int g = 0; g < 4; g++) bj[g] = bias[col0 + wn * 64 + g * 16 + nlow];

    if (out_mode == 1) {
        float* out = (float*)outall;
#pragma unroll
        for (int g = 0; g < 4; g++) {
            const int j = col0 + wn * 64 + g * 16 + nlow;
#pragma unroll
            for (int t = 0; t < 4; t++)
#pragma unroll
                for (int r = 0; r < 4; r++) {
                    const int i = row0 + wm * 64 + t * 16 + quad * 4 + r;
                    out[(long)i * 512 + j] = acc[t][g][r] + bj[g];
                }
        }
        return;
    }

    // bf16 epilogue: LDS round-trip (64 rows x 128 cols per half, pad 136)
    unsigned short* out = (unsigned short*)outall + (long)z * 4194304;
    for (int hf = 0; hf < 2; ++hf) {
        __syncthreads();
        if (wm == hf) {
#pragma unroll
            for (int t = 0; t < 4; t++)
#pragma unroll
                for (int g = 0; g < 4; g++)
#pragma unroll
                    for (int r = 0; r < 4; r++)
                        SM[(t * 16 + quad * 4 + r) * 136 + wn * 64 + g * 16 + nlow] =
                            f2bf(acc[t][g][r] + bj[g]);
        }
        __syncthreads();
#pragma unroll
        for (int c = 0; c < 4; c++) {
            const int idx = c * 256 + tid;
            const int row = idx >> 4, seg = idx & 15;
            const long gi = row0 + hf * 64 + row;
            *reinterpret_cast<short8*>(&out[gi * 512 + col0 + seg * 8]) =
                *reinterpret_cast<const short8*>(&SM[row * 136 + seg * 8]);
        }
    }
}

// ---------------------------------------------------------------------------
// Flash attention, fixed-offset softmax. qp/kp/vp/out: [B*S, 512] bf16.
// Block: 256 thr = 4 waves; wave w owns 16 queries; block owns 64 queries.
// ---------------------------------------------------------------------------
__global__ __launch_bounds__(256)
void attn_kernel(const unsigned short* __restrict__ qp,
                 const unsigned short* __restrict__ kp,
                 const unsigned short* __restrict__ vp,
                 const void* __restrict__ masked,
                 unsigned short* __restrict__ out)
{
    __shared__ unsigned short Ks[32][72];
    __shared__ unsigned short Vt[64][40];
    __shared__ unsigned short Ps[4][16][44];

    const int tid  = threadIdx.x;
    const int lane = tid & 63;
    const int w    = tid >> 6;
    const int quad = lane >> 4;
    const int nlow = lane & 15;

    const int b  = blockIdx.z;
    const int h  = blockIdx.y;
    const int q0 = blockIdx.x * 64 + w * 16;
    const long base = (long)b * 1048576 + h * 64;   // + s*512 + c

    const long long first = *reinterpret_cast<const long long*>(masked);
    int kmax;
    if ((first >> 32) != 0) kmax = reinterpret_cast<const int*>(masked)[b];
    else                    kmax = (int)reinterpret_cast<const long long*>(masked)[b];
    kmax = min(max(kmax, 1), 2048);

    const unsigned short* qrow = qp + base + (long)(q0 + nlow) * 512;
    const short8 aq0 = load8(qrow + quad * 8);
    const short8 aq1 = load8(qrow + 32 + quad * 8);

    short8 ones;
#pragma unroll
    for (int j = 0; j < 8; j++) ones[j] = (short)0x3F80;

    f32x4 o_acc[4], lacc;
#pragma unroll
    for (int vb = 0; vb < 4; vb++) o_acc[vb] = (f32x4){0.f, 0.f, 0.f, 0.f};
    lacc = (f32x4){0.f, 0.f, 0.f, 0.f};

    const int srow = tid >> 3;
    const int skk  = (tid & 7) * 8;
    const int kg   = srow >> 3;
    const int ko   = srow & 7;
    const int nkt  = (kmax + 31) >> 5;

    for (int kt = 0; kt < nkt; kt++) {
        const int k0 = kt * 32;
        *reinterpret_cast<short8*>(&Ks[srow][skk]) =
            load8(&kp[base + (long)(k0 + srow) * 512 + skk]);
        short8 vv = load8(&vp[base + (long)(k0 + srow) * 512 + skk]);
#pragma unroll
        for (int j = 0; j < 8; j++) {
            const int dh = skk + j;
            Vt[dh][((kg ^ ((dh >> 3) & 3)) << 3) + ko] = (unsigned short)vv[j];
        }
        __syncthreads();

        f32x4 sacc[2];
        sacc[0] = (f32x4){0.f, 0.f, 0.f, 0.f};
        sacc[1] = (f32x4){0.f, 0.f, 0.f, 0.f};
#pragma unroll
        for (int kb = 0; kb < 2; kb++) {
            short8 bk0 = load8(&Ks[kb * 16 + nlow][quad * 8]);
            short8 bk1 = load8(&Ks[kb * 16 + nlow][32 + quad * 8]);
            sacc[kb] = MFMA16(aq0, bk0, sacc[kb]);
            sacc[kb] = MFMA16(aq1, bk1, sacc[kb]);
        }

#pragma unroll
        for (int kb = 0; kb < 2; kb++) {
            const bool valid = (k0 + kb * 16 + nlow) < kmax;
#pragma unroll
            for (int r = 0; r < 4; r++) {
                const float e = valid ? fmaf(sacc[kb][r], SCALE_LOG2, -FIXED_M)
                                      : MASKED_E2;
                Ps[w][quad * 4 + r][kb * 16 + nlow] = f2bf(exp2f(e));
            }
        }
        __threadfence_block();

        const short4v apl = *reinterpret_cast<const short4v*>(&Ps[w][nlow][quad * 8]);
        const short4v aph = *reinterpret_cast<const short4v*>(&Ps[w][nlow][quad * 8 + 4]);
        short8 ap;
        ap[0] = apl[0]; ap[1] = apl[1]; ap[2] = apl[2]; ap[3] = apl[3];
        ap[4] = aph[0]; ap[5] = aph[1]; ap[6] = aph[2]; ap[7] = aph[3];

        lacc = MFMA16(ap, ones, lacc);
#pragma unroll
        for (int vb = 0; vb < 4; vb++) {
            const int dhr = vb * 16 + nlow;
            short8 bv = load8(&Vt[dhr][(quad ^ ((dhr >> 3) & 3)) << 3]);
            o_acc[vb] = MFMA16(ap, bv, o_acc[vb]);
        }
        __syncthreads();
    }

    float inv_l[4];
#pragma unroll
    for (int r = 0; r < 4; r++) inv_l[r] = 1.0f / lacc[r];
#pragma unroll
    for (int vb = 0; vb < 4; vb++) {
#pragma unroll
        for (int r = 0; r < 4; r++) {
            const int s   = q0 + quad * 4 + r;
            const int col = h * 64 + vb * 16 + nlow;
            out[(long)(b * 2048 + s) * 512 + col] = f2bf(o_acc[vb][r] * inv_l[r]);
        }
    }
}

// ---------------------------------------------------------------------------
// ws layout (u16 elems):
//   [0)          QKVb   3 x 4194304   (bf16 Q,K,V; region reused by ao)
//   [12582912)   Wb     4 x 262144
//   [13631488)   qp,kp,vp  3 x 4194304   (each flat [8192,512] bf16)
// ---------------------------------------------------------------------------
extern "C" void kernel_launch(void* const* d_in, const int* in_sizes, int n_in,
                              void* d_out, int out_size, void* d_ws, size_t ws_size,
                              hipStream_t stream)
{
    const float4* Q  = (const float4*)d_in[0];
    const float4* K  = (const float4*)d_in[1];
    const float4* V  = (const float4*)d_in[2];
    const float4* Wq = (const float4*)d_in[3];
    const float*  bq = (const float*)d_in[4];
    const float4* Wk = (const float4*)d_in[5];
    const float*  bk = (const float*)d_in[6];
    const float4* Wv = (const float4*)d_in[7];
    const float*  bv = (const float*)d_in[8];
    const float4* Wo = (const float4*)d_in[9];
    const float*  bo = (const float*)d_in[10];
    const void*   masked = d_in[11];

    unsigned short* ws16 = (unsigned short*)d_ws;
    unsigned short* QKVb = ws16;
    unsigned short* Wb   = ws16 + 12582912;
    unsigned short* qp   = ws16 + 13631488;
    unsigned short* kp   = qp + 4194304;
    unsigned short* vp   = kp + 4194304;
    unsigned short* ao   = ws16;  // alias Qb: consumed before attn writes ao

    convert_bf16<<<2048, 256, 0, stream>>>(Q, K, V, Wq, Wk, Wv, Wo, (u16x4*)ws16);
    gemm_bf<<<dim3(256, 3), 256, 0, stream>>>(QKVb, Wb, bq, bk, bv, qp, 0);
    attn_kernel<<<dim3(32, 8, 4), 256, 0, stream>>>(qp, kp, vp, masked, ao);
    gemm_bf<<<dim3(256, 1), 256, 0, stream>>>(ao, Wb + 3 * 262144, bo, bo, bo,
                                              d_out, 1);
}